// Round 1
// baseline (36945.901 us; speedup 1.0000x reference)
//
#include <hip/hip_runtime.h>

typedef unsigned short u16;
typedef __attribute__((ext_vector_type(8))) short bf16x8;
typedef __attribute__((ext_vector_type(4))) float f32x4;

#define MFMA(a,b,c) __builtin_amdgcn_mfma_f32_16x16x32_bf16(a,b,c,0,0,0)

#define B_   128
#define T_   200
#define F_   171
#define FP_  192          // padded frame (6 K-chunks of 32)
#define H_   1024
#define G_   4096
#define K1_  1216         // FP_ + H_
#define K2_  2048         // H_ + H_
#define TF_  (T_*F_)      // 34200
#define BH_  (B_*H_)
#define NB_  256
#define NT_  256

__device__ __forceinline__ u16 f2bf(float v){
  union { float f; unsigned u; } c; c.f = v;
  unsigned r = (c.u + 0x7fffu + ((c.u >> 16) & 1u)) >> 16;   // RNE
  return (u16)r;
}
__device__ __forceinline__ float bf2f(u16 h){
  union { unsigned u; float f; } c; c.u = ((unsigned)h) << 16; return c.f;
}
__device__ __forceinline__ bf16x8 ld8(const u16* p){
  return *reinterpret_cast<const bf16x8*>(p);
}
__device__ __forceinline__ float sigm(float v){ return 1.f / (1.f + __expf(-v)); }

// ---------------- device-wide barrier (grid = 256 co-resident blocks) ----------------
__device__ __forceinline__ void gbar(unsigned* cnt, unsigned ep, int tid){
  __syncthreads();
  if (tid == 0){
    __threadfence();                 // release: make our h/c stores visible device-wide
    atomicAdd(cnt, 1u);
    const unsigned tgt = ep * (unsigned)NB_;
    while (__hip_atomic_load(cnt, __ATOMIC_RELAXED, __HIP_MEMORY_SCOPE_AGENT) < tgt)
      __builtin_amdgcn_s_sleep(1);
    __threadfence();                 // acquire: invalidate stale cached lines
  }
  __syncthreads();
}

// ---------------- gate tile -> cell update ----------------
// lds[gate 0..3][32 batch][16 units]; block owns batches mg*32..+32, units ng*16..+16
__device__ __forceinline__ void stage_fin(
    f32x4 a0, f32x4 a1, const float* __restrict__ bias_l, float* __restrict__ c_l,
    u16* __restrict__ ohh, u16* __restrict__ ohl,
    int mg, int ng, int wn, int tid, int lane, float (*lds)[32][17])
{
  const int r16 = lane & 15, ke = lane >> 4;
  const float bs = bias_l[ng*64 + wn*16 + r16];     // acc col = lane&15
#pragma unroll
  for (int r = 0; r < 4; ++r){                      // D: col=lane&15, row=(lane>>4)*4+r
    lds[wn][ke*4 + r][r16]      = a0[r] + bs;
    lds[wn][16 + ke*4 + r][r16] = a1[r] + bs;
  }
  __syncthreads();
  for (int e = tid; e < 512; e += NT_){
    const int b_loc = e >> 4, u = e & 15;
    const float gi = lds[0][b_loc][u], gf = lds[1][b_loc][u];
    const float gg = lds[2][b_loc][u], go = lds[3][b_loc][u];
    const int idx = (mg*32 + b_loc)*H_ + ng*16 + u;
    const float co = c_l[idx];
    const float cn = sigm(gf)*co + sigm(gi)*tanhf(gg);
    const float hn = sigm(go)*tanhf(cn);
    c_l[idx] = cn;
    const u16 hh = f2bf(hn);
    ohh[idx] = hh;
    ohl[idx] = f2bf(hn - bf2f(hh));
  }
}

// ---------------- H x H layer (L2 / L3): gates = [x_cur | h_prev] * Wcat^T ----------------
__device__ __forceinline__ void layer_hh(
    const u16* __restrict__ axh, const u16* __restrict__ axl,   // lower-layer h (current step)
    const u16* __restrict__ ahh, const u16* __restrict__ ahl,   // own h (prev step)
    const u16* __restrict__ W, const float* __restrict__ bias_l,
    float* __restrict__ c_l, u16* __restrict__ ohh, u16* __restrict__ ohl,
    int mg, int ng, int wn, int tid, int lane, float (*lds)[32][17])
{
  const int r16 = lane & 15, ke = lane >> 4;
  const u16* wp = W + (size_t)(ng*64 + wn*16 + r16)*K2_ + ke*8;
  const int b0 = mg*32 + r16, b1 = b0 + 16;
  const int o0 = b0*H_ + ke*8, o1 = b1*H_ + ke*8;
  f32x4 a0 = {0,0,0,0}, a1 = {0,0,0,0};
#pragma unroll 2
  for (int kc = 0; kc < 32; ++kc){
    bf16x8 bw  = ld8(wp + kc*32);
    bf16x8 p0h = ld8(axh + o0 + kc*32), p0l = ld8(axl + o0 + kc*32);
    bf16x8 p1h = ld8(axh + o1 + kc*32), p1l = ld8(axl + o1 + kc*32);
    a0 = MFMA(p0h, bw, a0); a1 = MFMA(p1h, bw, a1);
    a0 = MFMA(p0l, bw, a0); a1 = MFMA(p1l, bw, a1);
  }
#pragma unroll 2
  for (int kc = 0; kc < 32; ++kc){
    bf16x8 bw  = ld8(wp + H_ + kc*32);
    bf16x8 p0h = ld8(ahh + o0 + kc*32), p0l = ld8(ahl + o0 + kc*32);
    bf16x8 p1h = ld8(ahh + o1 + kc*32), p1l = ld8(ahl + o1 + kc*32);
    a0 = MFMA(p0h, bw, a0); a1 = MFMA(p1h, bw, a1);
    a0 = MFMA(p0l, bw, a0); a1 = MFMA(p1l, bw, a1);
  }
  stage_fin(a0, a1, bias_l, c_l, ohh, ohl, mg, ng, wn, tid, lane, lds);
}

// ---------------- main persistent kernel ----------------
__global__ __launch_bounds__(NT_) void k_main(
    const float* __restrict__ x, float* __restrict__ out,
    const u16* __restrict__ W1, const u16* __restrict__ W2,
    const u16* __restrict__ W3, const u16* __restrict__ WD,
    const float* __restrict__ bperm, const float* __restrict__ bdec,
    u16* __restrict__ h_hi, u16* __restrict__ h_lo, float* __restrict__ cst,
    u16* __restrict__ if_hi, u16* __restrict__ if_lo,
    unsigned* __restrict__ bar)
{
  const int tid = threadIdx.x, bid = blockIdx.x;
  const int mg = bid >> 6, ng = bid & 63;           // 4 batch-groups x 64 gate-groups
  const int wn = tid >> 6, lane = tid & 63;         // wave = gate type (i,f,g,o)
  const int r16 = lane & 15, ke = lane >> 4;
  __shared__ float lds[4][32][17];
  unsigned ep = 0;

  for (int t = 0; t < T_; ++t){
    const int cur = t & 1, prv = cur ^ 1;

    // ---------- L1: gates = [in_frame | h0_prev] * Wcat1^T ----------
    {
      const u16* ahh = h_hi + (0*2+prv)*BH_;
      const u16* ahl = h_lo + (0*2+prv)*BH_;
      const u16* wp = W1 + (size_t)(ng*64 + wn*16 + r16)*K1_ + ke*8;
      const int b0 = mg*32 + r16, b1 = b0 + 16;
      const int x0 = b0*FP_ + ke*8, x1 = b1*FP_ + ke*8;
      const int o0 = b0*H_ + ke*8, o1 = b1*H_ + ke*8;
      f32x4 a0 = {0,0,0,0}, a1 = {0,0,0,0};
#pragma unroll 2
      for (int kc = 0; kc < 6; ++kc){
        bf16x8 bw  = ld8(wp + kc*32);
        bf16x8 p0h = ld8(if_hi + x0 + kc*32), p0l = ld8(if_lo + x0 + kc*32);
        bf16x8 p1h = ld8(if_hi + x1 + kc*32), p1l = ld8(if_lo + x1 + kc*32);
        a0 = MFMA(p0h, bw, a0); a1 = MFMA(p1h, bw, a1);
        a0 = MFMA(p0l, bw, a0); a1 = MFMA(p1l, bw, a1);
      }
#pragma unroll 2
      for (int kc = 0; kc < 32; ++kc){
        bf16x8 bw  = ld8(wp + FP_ + kc*32);
        bf16x8 p0h = ld8(ahh + o0 + kc*32), p0l = ld8(ahl + o0 + kc*32);
        bf16x8 p1h = ld8(ahh + o1 + kc*32), p1l = ld8(ahl + o1 + kc*32);
        a0 = MFMA(p0h, bw, a0); a1 = MFMA(p1h, bw, a1);
        a0 = MFMA(p0l, bw, a0); a1 = MFMA(p1l, bw, a1);
      }
      stage_fin(a0, a1, bperm + 0*G_, cst + 0*BH_,
                h_hi + (0*2+cur)*BH_, h_lo + (0*2+cur)*BH_,
                mg, ng, wn, tid, lane, lds);
    }
    ++ep; gbar(bar, ep, tid);

    // ---------- L2 ----------
    layer_hh(h_hi+(0*2+cur)*BH_, h_lo+(0*2+cur)*BH_,
             h_hi+(1*2+prv)*BH_, h_lo+(1*2+prv)*BH_,
             W2, bperm + 1*G_, cst + 1*BH_,
             h_hi+(1*2+cur)*BH_, h_lo+(1*2+cur)*BH_,
             mg, ng, wn, tid, lane, lds);
    ++ep; gbar(bar, ep, tid);

    // ---------- L3 ----------
    layer_hh(h_hi+(1*2+cur)*BH_, h_lo+(1*2+cur)*BH_,
             h_hi+(2*2+prv)*BH_, h_lo+(2*2+prv)*BH_,
             W3, bperm + 2*G_, cst + 2*BH_,
             h_hi+(2*2+cur)*BH_, h_lo+(2*2+cur)*BH_,
             mg, ng, wn, tid, lane, lds);
    ++ep; gbar(bar, ep, tid);

    // ---------- decoder: out = h2 * Wdec^T + b; prepare next in_frame ----------
    if (bid < 88){                                   // 8 batch-tiles x 11 col-tiles
      const int mb = bid / 11, nt = bid % 11;
      const u16* h2h = h_hi + (2*2+cur)*BH_;
      const u16* h2l = h_lo + (2*2+cur)*BH_;
      const u16* wp = WD + (size_t)(nt*16 + r16)*H_ + ke*8;
      const int b0 = mb*16 + r16;
      const int o0 = b0*H_ + ke*8;
      f32x4 a0 = {0,0,0,0};
      for (int kc = wn*8; kc < wn*8 + 8; ++kc){      // 4 waves split K
        bf16x8 bw = ld8(wp + kc*32);
        bf16x8 ph = ld8(h2h + o0 + kc*32), pl = ld8(h2l + o0 + kc*32);
        a0 = MFMA(ph, bw, a0);
        a0 = MFMA(pl, bw, a0);
      }
#pragma unroll
      for (int r = 0; r < 4; ++r) lds[wn][ke*4 + r][r16] = a0[r];
      __syncthreads();
      {
        const int b_loc = tid >> 4, f_loc = tid & 15;     // 256 threads = 16x16 tile
        float v = lds[0][b_loc][f_loc] + lds[1][b_loc][f_loc]
                + lds[2][b_loc][f_loc] + lds[3][b_loc][f_loc] + bdec[nt*16 + f_loc];
        const int f = nt*16 + f_loc, b = mb*16 + b_loc;
        if (f < F_) out[(size_t)b*TF_ + (size_t)t*F_ + f] = v;
        if (t + 1 < T_){
          float in = 0.f;
          if (f < F_){
            const bool gt = (((t+1) % 10) < 5);
            in = gt ? x[(size_t)b*TF_ + (size_t)(t+1)*F_ + f] : v;
          }
          const u16 hh = f2bf(in);
          if_hi[b*FP_ + f] = hh;
          if_lo[b*FP_ + f] = f2bf(in - bf2f(hh));
        }
      }
    }
    ++ep; gbar(bar, ep, tid);
  }
}

// ---------------- prep: permuted biases, decoder bias, initial in_frame ----------------
__global__ void k_prep(const float* __restrict__ x,
                       const float* bi1, const float* bh1,
                       const float* bi2, const float* bh2,
                       const float* bi3, const float* bh3,
                       const float* bd_in,
                       float* __restrict__ bperm, float* __restrict__ bdec,
                       u16* __restrict__ if_hi, u16* __restrict__ if_lo)
{
  const int i = blockIdx.x * blockDim.x + threadIdx.x;
  if (i < 3*G_){
    const int l = i >> 12, r = i & 4095;
    const int ng = r >> 6, g = (r >> 4) & 3, u = r & 15;
    const int j = (g << 10) | (ng << 4) | u;          // original gate row
    const float* bi = (l == 0) ? bi1 : (l == 1) ? bi2 : bi3;
    const float* bh = (l == 0) ? bh1 : (l == 1) ? bh2 : bh3;
    bperm[i] = bi[j] + bh[j];
  }
  const int i2 = i - 3*G_;
  if (i2 >= 0 && i2 < FP_) bdec[i2] = (i2 < F_) ? bd_in[i2] : 0.f;
  const int i3 = i2 - FP_;
  if (i3 >= 0 && i3 < B_*FP_){
    const int b = i3 / FP_, f = i3 - b*FP_;
    const float v = (f < F_) ? x[(size_t)b*TF_ + f] : 0.f;   // t=0 is ground-truth
    const u16 hh = f2bf(v);
    if_hi[i3] = hh;
    if_lo[i3] = f2bf(v - bf2f(hh));
  }
}

// ---------------- weight convert: fp32 -> bf16, gate-permuted & concatenated ----------------
__global__ void k_wcvt(const float* __restrict__ Wih1, const float* __restrict__ Whh1,
                       const float* __restrict__ Wih2, const float* __restrict__ Whh2,
                       const float* __restrict__ Wih3, const float* __restrict__ Whh3,
                       const float* __restrict__ Wd_in,
                       u16* __restrict__ W1, u16* __restrict__ W2,
                       u16* __restrict__ W3, u16* __restrict__ WD)
{
  const int region = blockIdx.y;
  const size_t stride = (size_t)gridDim.x * blockDim.x;
  const size_t i0 = (size_t)blockIdx.x * blockDim.x + threadIdx.x;
  if (region == 0){
    for (size_t i = i0; i < (size_t)G_*K1_; i += stride){
      const int r = (int)(i / K1_), k = (int)(i - (size_t)r*K1_);
      const int ng = r >> 6, g = (r >> 4) & 3, u = r & 15;
      const int j = (g << 10) | (ng << 4) | u;
      float v;
      if (k < FP_) v = (k < F_) ? Wih1[(size_t)j*F_ + k] : 0.f;
      else         v = Whh1[(size_t)j*H_ + (k - FP_)];
      W1[i] = f2bf(v);
    }
  } else if (region == 1){
    for (size_t i = i0; i < (size_t)G_*K2_; i += stride){
      const int r = (int)(i / K2_), k = (int)(i - (size_t)r*K2_);
      const int ng = r >> 6, g = (r >> 4) & 3, u = r & 15;
      const int j = (g << 10) | (ng << 4) | u;
      const float v = (k < H_) ? Wih2[(size_t)j*H_ + k] : Whh2[(size_t)j*H_ + (k - H_)];
      W2[i] = f2bf(v);
    }
  } else if (region == 2){
    for (size_t i = i0; i < (size_t)G_*K2_; i += stride){
      const int r = (int)(i / K2_), k = (int)(i - (size_t)r*K2_);
      const int ng = r >> 6, g = (r >> 4) & 3, u = r & 15;
      const int j = (g << 10) | (ng << 4) | u;
      const float v = (k < H_) ? Wih3[(size_t)j*H_ + k] : Whh3[(size_t)j*H_ + (k - H_)];
      W3[i] = f2bf(v);
    }
  } else {
    for (size_t i = i0; i < (size_t)176*H_; i += stride){
      const int r = (int)(i >> 10), k = (int)(i & (H_ - 1));
      WD[i] = f2bf((r < F_) ? Wd_in[(size_t)r*H_ + k] : 0.f);
    }
  }
}

extern "C" void kernel_launch(void* const* d_in, const int* in_sizes, int n_in,
                              void* d_out, int out_size, void* d_ws, size_t ws_size,
                              hipStream_t stream)
{
  const float* x    = (const float*)d_in[0];
  const float* Wih1 = (const float*)d_in[1];
  const float* bih1 = (const float*)d_in[2];
  const float* Whh1 = (const float*)d_in[3];
  const float* bhh1 = (const float*)d_in[4];
  const float* Wih2 = (const float*)d_in[5];
  const float* bih2 = (const float*)d_in[6];
  const float* Whh2 = (const float*)d_in[7];
  const float* bhh2 = (const float*)d_in[8];
  const float* Wih3 = (const float*)d_in[9];
  const float* bih3 = (const float*)d_in[10];
  const float* Whh3 = (const float*)d_in[11];
  const float* bhh3 = (const float*)d_in[12];
  const float* Wdec = (const float*)d_in[13];
  const float* bdec_in = (const float*)d_in[14];
  float* out = (float*)d_out;

  char* ws = (char*)d_ws;
  size_t off = 0;
  auto alloc = [&](size_t bytes) -> void* {
    void* p = ws + off;
    off = (off + bytes + 255) & ~(size_t)255;
    return p;
  };
  unsigned* bar = (unsigned*)alloc(256);
  u16* h_hi  = (u16*)alloc((size_t)3*2*BH_*2);
  u16* h_lo  = (u16*)alloc((size_t)3*2*BH_*2);
  float* cst = (float*)alloc((size_t)3*BH_*4);
  u16* if_hi = (u16*)alloc((size_t)B_*FP_*2);
  u16* if_lo = (u16*)alloc((size_t)B_*FP_*2);
  const size_t zero_bytes = off;                 // state zone: re-zeroed every launch
  u16* W1 = (u16*)alloc((size_t)G_*K1_*2);
  u16* W2 = (u16*)alloc((size_t)G_*K2_*2);
  u16* W3 = (u16*)alloc((size_t)G_*K2_*2);
  u16* WD = (u16*)alloc((size_t)176*H_*2);
  float* bperm = (float*)alloc((size_t)3*G_*4);
  float* bdec  = (float*)alloc((size_t)FP_*4);

  hipMemsetAsync(d_ws, 0, zero_bytes, stream);
  k_prep<<<145, 256, 0, stream>>>(x, bih1, bhh1, bih2, bhh2, bih3, bhh3, bdec_in,
                                  bperm, bdec, if_hi, if_lo);
  k_wcvt<<<dim3(2048, 4), 256, 0, stream>>>(Wih1, Whh1, Wih2, Whh2, Wih3, Whh3, Wdec,
                                            W1, W2, W3, WD);
  k_main<<<NB_, NT_, 0, stream>>>(x, out, W1, W2, W3, WD, bperm, bdec,
                                  h_hi, h_lo, cst, if_hi, if_lo, bar);
}